// Round 1
// 297.751 us; speedup vs baseline: 1.0226x; 1.0226x over previous
//
#include <hip/hip_runtime.h>
#include <stdint.h>
#include <math.h>

#define FIN 128

typedef __attribute__((ext_vector_type(8))) short short8v;
typedef __attribute__((ext_vector_type(4))) float float4v;
typedef __attribute__((ext_vector_type(2))) float float2v;

// ---------------- bf16 helpers ----------------
// gfx950 has v_cvt_pk_bf16_f32 (RNE): D.lo = bf16(S0), D.hi = bf16(S1).
// Replaces ~7 integer ops per pair with 1 instruction.
__device__ __forceinline__ uint32_t f2_to_bf2(float x, float y) {
    uint32_t r;
    asm("v_cvt_pk_bf16_f32 %0, %1, %2" : "=v"(r) : "v"(x), "v"(y));
    return r;
}
__device__ __forceinline__ unsigned short f_to_bf(float x) {
    union { float f; uint32_t i; } a;
    a.f = x;
    uint32_t u = a.i + 0x7FFF + ((a.i >> 16) & 1);
    return (unsigned short)(u >> 16);
}
// acc2[0..7] (+)= 16 fp8 decoded (packed adds)
__device__ __forceinline__ void acc16_fp8_pk(float2v* acc2, uint4 v) {
    uint32_t us[4] = {v.x, v.y, v.z, v.w};
#pragma unroll
    for (int q = 0; q < 4; ++q) {
        acc2[q * 2 + 0] += __builtin_amdgcn_cvt_pk_f32_fp8(us[q], false);
        acc2[q * 2 + 1] += __builtin_amdgcn_cvt_pk_f32_fp8(us[q], true);
    }
}

__device__ __forceinline__ int edge_at(const void* ei, long long idx, int is32) {
    return is32 ? ((const int*)ei)[idx] : (int)((const long long*)ei)[idx];
}

// ---------------- Level-1 split (16 super-bins, dst>>13) + inline dtype detect ------
// record = (src<<13)|(dst&8191), 30 bits (requires n < 2^19; here n = 100000)
#define SP_CHUNK 4096
__global__ __launch_bounds__(256) void splitA_kernel(const void* __restrict__ ei,
                                                     int* __restrict__ gCnt,
                                                     uint32_t* __restrict__ buf1,
                                                     int E, int capS) {
    __shared__ int hist[16];
    __shared__ int gbase[16];
    __shared__ int lflag;
    int t = threadIdx.x;
    if (t < 16) hist[t] = 0;
    if (t == 0) lflag = 0;
    long long base = (long long)blockIdx.x * SP_CHUNK;
    __syncthreads();
    {
        long long e = base + t;
        if (e < E && ((const int*)ei)[2 * e + 1] != 0) atomicOr(&lflag, 1);
    }
    __syncthreads();
    int is32 = lflag;
    uint32_t lrec[16], rec[16];
#pragma unroll
    for (int j = 0; j < 16; ++j) {
        long long e = base + t + j * 256;
        if (e < E) {
            int s = edge_at(ei, e, is32);
            int d = edge_at(ei, (long long)E + e, is32);
            int b = d >> 13;
            int lofs = atomicAdd(&hist[b], 1);
            lrec[j] = ((uint32_t)lofs << 4) | (uint32_t)b;
            rec[j] = ((uint32_t)s << 13) | (uint32_t)(d & 8191);
        } else
            lrec[j] = 0xFFFFFFFFu;
    }
    __syncthreads();
    if (t < 16) gbase[t] = atomicAdd(&gCnt[t], hist[t]);
    __syncthreads();
#pragma unroll
    for (int j = 0; j < 16; ++j) {
        if (lrec[j] != 0xFFFFFFFFu) {
            int b = lrec[j] & 15;
            int pos = gbase[b] + (int)(lrec[j] >> 4);
            if (pos < capS) buf1[(size_t)b * capS + pos] = rec[j];
        }
    }
}

// ---------------- Level-2 split: 128 sub-bins of 64 nodes ----------------
__global__ __launch_bounds__(256) void splitB_kernel(const int* __restrict__ gCnt,
                                                     const uint32_t* __restrict__ buf1,
                                                     int* __restrict__ cnt2,
                                                     uint32_t* __restrict__ buf2,
                                                     int capS, int cap2, int NB) {
    __shared__ int hist[128];
    __shared__ int gbase[128];
    int t = threadIdx.x;
    int s = blockIdx.y;
    if (t < 128) hist[t] = 0;
    __syncthreads();
    int m = gCnt[s];
    if (m > capS) m = capS;
    long long base = (long long)blockIdx.x * SP_CHUNK;
    uint32_t lrec[16], r32[16];
#pragma unroll
    for (int j = 0; j < 16; ++j) {
        long long i = base + t + j * 256;
        if (i < m) {
            uint32_t r = buf1[(size_t)s * capS + i];
            int d13 = (int)(r & 8191u);
            int sub = d13 >> 6;
            int lofs = atomicAdd(&hist[sub], 1);
            lrec[j] = ((uint32_t)lofs << 7) | (uint32_t)sub;
            r32[j] = ((r >> 13) << 6) | (uint32_t)(d13 & 63);
        } else
            lrec[j] = 0xFFFFFFFFu;
    }
    __syncthreads();
    if (t < 128) {
        int g = s * 128 + t;
        gbase[t] = (g < NB) ? atomicAdd(&cnt2[g], hist[t]) : 0;
    }
    __syncthreads();
#pragma unroll
    for (int j = 0; j < 16; ++j) {
        if (lrec[j] != 0xFFFFFFFFu) {
            int sub = lrec[j] & 127;
            int pos = gbase[sub] + (int)(lrec[j] >> 7);
            if (pos < cap2) buf2[(size_t)(s * 128 + sub) * cap2 + pos] = r32[j];
        }
    }
}

// ---------------- merged: degree+dinv+rowend (fixed bin-base) + CSR scatter --------
__global__ __launch_bounds__(256) void binBC_kernel(const int* __restrict__ cnt2,
                                                    const uint32_t* __restrict__ buf2,
                                                    int* __restrict__ cnt,
                                                    float* __restrict__ dinv,
                                                    int* __restrict__ rowend,
                                                    int* __restrict__ col,
                                                    int n, int cap2) {
    __shared__ int h[64];
    __shared__ int rowst[64];
    __shared__ int cur[64];
    __shared__ int sc[64];
    int bin = blockIdx.x;
    int t = threadIdx.x;
    if (t < 64) { h[t] = 0; cur[t] = 0; }
    __syncthreads();
    int m = cnt2[bin];
    if (m > cap2) m = cap2;
    const uint32_t* buf = buf2 + (size_t)bin * cap2;
    for (int i = t; i < m; i += 256) atomicAdd(&h[buf[i] & 63], 1);
    __syncthreads();
    int c = 0;
    if (t < 64) { c = h[t]; sc[t] = c; }
    __syncthreads();
    for (int off = 1; off < 64; off <<= 1) {
        int v = 0;
        if (t < 64 && t >= off) v = sc[t - off];
        __syncthreads();
        if (t < 64) sc[t] += v;
        __syncthreads();
    }
    if (t < 64) {
        int node = bin * 64 + t;
        int base = bin * cap2;
        rowst[t] = base + sc[t] - c;
        if (node < n) {
            cnt[node] = c;
            dinv[node] = rsqrtf((float)c + 1.0f);
            rowend[node] = base + sc[t];
        }
    }
    __syncthreads();
    for (int i = t; i < m; i += 256) {
        uint32_t rec = buf[i];
        int d6 = rec & 63;
        int off = atomicAdd(&cur[d6], 1);
        col[rowst[d6] + off] = (int)(rec >> 6);
    }
}

// ---------------- W -> fragment-ordered bf16 ----------------
__global__ __launch_bounds__(256) void wconv_all(const float* __restrict__ W1,
                                                 const float* __restrict__ W2,
                                                 const float* __restrict__ W3,
                                                 unsigned short* __restrict__ Wf1,
                                                 unsigned short* __restrict__ Wf2,
                                                 unsigned short* __restrict__ Wf3) {
    int idx = blockIdx.x * 256 + threadIdx.x;
    const float* W;
    unsigned short* Wf;
    int NCOL, base;
    if (idx < 2048)      { W = W1; Wf = Wf1; NCOL = 128; base = idx; }
    else if (idx < 4096) { W = W2; Wf = Wf2; NCOL = 128; base = idx - 2048; }
    else if (idx < 5120) { W = W3; Wf = Wf3; NCOL = 64;  base = idx - 4096; }
    else return;
    int f = base >> 6, l = base & 63;
    int ct = f >> 2, ks = f & 3;
    int nn = ct * 16 + (l & 15);
    int k0 = ks * 32 + (l >> 4) * 8;
    uint32_t pk[4];
#pragma unroll
    for (int j = 0; j < 4; ++j) {
        float a = W[(size_t)(k0 + 2 * j) * NCOL + nn];
        float b = W[(size_t)(k0 + 2 * j + 1) * NCOL + nn];
        pk[j] = f2_to_bf2(a, b);
    }
    uint4 v = make_uint4(pk[0], pk[1], pk[2], pk[3]);
    ((uint4*)Wf)[base] = v;
}

// ---------------- MFMA GEMM + dinv row-scale epilogue; OUT_FP8 packs e4m3 ----------
template <int NCOL, int A_FP32, int OUT_FP8>
__global__ __launch_bounds__(256) void gemm_mfma(const void* __restrict__ Av,
                                                 const unsigned short* __restrict__ Wf,
                                                 const float* __restrict__ dinv,
                                                 void* __restrict__ Cv, int n) {
    __shared__ unsigned short lds[NCOL * 128];
    const int t = threadIdx.x;
    for (int i = t; i < NCOL * 16; i += 256)
        ((uint4*)lds)[i] = ((const uint4*)Wf)[i];
    __syncthreads();

    const int wave = t >> 6, lane = t & 63;
    const int row0 = blockIdx.x * 64 + wave * 16;
    const int m = lane & 15, quad = lane >> 4;
    int arow = row0 + m;
    if (arow >= n) arow = n - 1;

    short8v a[4];
    if (A_FP32) {
        const float* A = (const float*)Av;
#pragma unroll
        for (int ks = 0; ks < 4; ++ks) {
            float4 lo = *(const float4*)(A + (size_t)arow * 128 + ks * 32 + quad * 8);
            float4 hi = *(const float4*)(A + (size_t)arow * 128 + ks * 32 + quad * 8 + 4);
            union { short8v v; uint32_t u[4]; } pk;
            pk.u[0] = f2_to_bf2(lo.x, lo.y);
            pk.u[1] = f2_to_bf2(lo.z, lo.w);
            pk.u[2] = f2_to_bf2(hi.x, hi.y);
            pk.u[3] = f2_to_bf2(hi.z, hi.w);
            a[ks] = pk.v;
        }
    } else {
        const unsigned short* A = (const unsigned short*)Av;
#pragma unroll
        for (int ks = 0; ks < 4; ++ks)
            a[ks] = *(const short8v*)(A + (size_t)arow * 128 + ks * 32 + quad * 8);
    }

    const int cr0 = row0 + quad * 4;
    float ds[4];
#pragma unroll
    for (int r = 0; r < 4; ++r) {
        int gr = cr0 + r;
        ds[r] = (gr < n) ? dinv[gr] : 0.0f;
    }
#pragma unroll
    for (int ct = 0; ct < NCOL / 16; ++ct) {
        float4v acc = {0.0f, 0.0f, 0.0f, 0.0f};
#pragma unroll
        for (int ks = 0; ks < 4; ++ks) {
            int f = ct * 4 + ks;
            short8v b = *(const short8v*)(lds + ((size_t)(f * 64 + lane)) * 8);
            acc = __builtin_amdgcn_mfma_f32_16x16x32_bf16(a[ks], b, acc, 0, 0, 0);
        }
#pragma unroll
        for (int r = 0; r < 4; ++r) {
            int gr = cr0 + r;
            if (gr < n) {
                float val = acc[r] * ds[r];
                if (OUT_FP8) {
                    int u = __builtin_amdgcn_cvt_pk_fp8_f32(val, val, 0, false);
                    ((unsigned char*)Cv)[(size_t)gr * NCOL + ct * 16 + m] =
                        (unsigned char)(u & 0xFF);
                } else {
                    ((unsigned short*)Cv)[(size_t)gr * NCOL + ct * 16 + m] = f_to_bf(val);
                }
            }
        }
    }
}

// ---------------- 2-node aggregation, 128 feats, fp8 T (128B rows) ----------------
// sel=lane>>5 (node), slot=(lane>>3)&3 (4 edge slots), j=lane&7 (16-feat octet).
// Tail masking via sentinel zero-row (index n -> bytes [n*128, n*128+128), zeroed):
// cmp + 1 cndmask on the index instead of clamp + 4 cndmask on the data.
__global__ __launch_bounds__(256) void agg_relu_128_fp8(
        const uint32_t* __restrict__ T8, const int* __restrict__ rowend,
        const int* __restrict__ cnt, const int* __restrict__ col,
        const float* __restrict__ dinv, const float* __restrict__ bias,
        uint32_t* __restrict__ outHb, int n) {
    int wid = blockIdx.x * 4 + (threadIdx.x >> 6);
    int lane = threadIdx.x & 63;
    int sel = lane >> 5, slot = (lane >> 3) & 3, j = lane & 7;
    int nodeA = wid * 2;
    int node = nodeA + sel;
    if (nodeA >= n) return;
    bool valid = node < n;
    int nd = valid ? node : nodeA;
    int end = rowend[nd];
    int start = end - cnt[nd];
    if (!valid) start = end;

    float2v acc2[8];
#pragma unroll
    for (int k = 0; k < 8; ++k) acc2[k] = (float2v){0.0f, 0.0f};
    if (slot == 0 && valid) {
        uint4 v = *(const uint4*)(T8 + (size_t)node * 32 + j * 4);
        acc16_fp8_pk(acc2, v);
    }
    int deg = end - start;
    int degM = max(deg, __shfl_xor(deg, 32, 64));
    int p = start + slot;
    const int ZR = n;  // sentinel zero row
    for (int it = 0; it < degM; it += 8) {
        int e0 = p, e1 = p + 4;
        int s0 = col[e0], s1 = col[e1];   // col padded: unclamped read is safe
        if (e0 >= end) s0 = ZR;
        if (e1 >= end) s1 = ZR;
        uint4 v0 = *(const uint4*)(T8 + (size_t)s0 * 32 + j * 4);
        uint4 v1 = *(const uint4*)(T8 + (size_t)s1 * 32 + j * 4);
        acc16_fp8_pk(acc2, v0);
        acc16_fp8_pk(acc2, v1);
        p += 8;
    }
    float* acc = (float*)acc2;
#pragma unroll
    for (int k = 0; k < 16; ++k) {
        acc[k] += __shfl_xor(acc[k], 8, 64);
        acc[k] += __shfl_xor(acc[k], 16, 64);
    }
    if (slot == 0 && valid) {
        float di = dinv[node];
        const float4* b4 = (const float4*)bias;
        float r[16];
#pragma unroll
        for (int q = 0; q < 4; ++q) {
            float4 bb = b4[j * 4 + q];
            r[q * 4 + 0] = fmaxf(di * acc[q * 4 + 0] + bb.x, 0.0f);
            r[q * 4 + 1] = fmaxf(di * acc[q * 4 + 1] + bb.y, 0.0f);
            r[q * 4 + 2] = fmaxf(di * acc[q * 4 + 2] + bb.z, 0.0f);
            r[q * 4 + 3] = fmaxf(di * acc[q * 4 + 3] + bb.w, 0.0f);
        }
        uint4 o0, o1;
        o0.x = f2_to_bf2(r[0], r[1]);   o0.y = f2_to_bf2(r[2], r[3]);
        o0.z = f2_to_bf2(r[4], r[5]);   o0.w = f2_to_bf2(r[6], r[7]);
        o1.x = f2_to_bf2(r[8], r[9]);   o1.y = f2_to_bf2(r[10], r[11]);
        o1.z = f2_to_bf2(r[12], r[13]); o1.w = f2_to_bf2(r[14], r[15]);
        *(uint4*)(outHb + (size_t)node * 64 + j * 8) = o0;
        *(uint4*)(outHb + (size_t)node * 64 + j * 8 + 4) = o1;
    }
}

// ---------------- 2-node aggregation, 64 feats fp8 (64B rows) + log_softmax --------
// sel=lane>>5, slot=(lane>>2)&7 (8 edge slots), j=lane&3 (16-feat octet of 64).
// Sentinel zero row index = 2n (64B rows -> bytes [n*128, n*128+64), zeroed).
__global__ __launch_bounds__(256) void agg_lsm_64_fp8(
        const uint32_t* __restrict__ T8, const int* __restrict__ rowend,
        const int* __restrict__ cnt, const int* __restrict__ col,
        const float* __restrict__ dinv, const float* __restrict__ bias,
        float* __restrict__ out, int n) {
    int wid = blockIdx.x * 4 + (threadIdx.x >> 6);
    int lane = threadIdx.x & 63;
    int sel = lane >> 5, slot = (lane >> 2) & 7, j = lane & 3;
    int nodeA = wid * 2;
    int node = nodeA + sel;
    if (nodeA >= n) return;
    bool valid = node < n;
    int nd = valid ? node : nodeA;
    int end = rowend[nd];
    int start = end - cnt[nd];
    if (!valid) start = end;

    float2v acc2[8];
#pragma unroll
    for (int k = 0; k < 8; ++k) acc2[k] = (float2v){0.0f, 0.0f};
    if (slot == 0 && valid) {
        uint4 v = *(const uint4*)(T8 + (size_t)node * 16 + j * 4);
        acc16_fp8_pk(acc2, v);
    }
    int deg = end - start;
    int degM = max(deg, __shfl_xor(deg, 32, 64));
    int p = start + slot;
    const int ZR = 2 * n;  // sentinel zero row (64B stride)
    for (int it = 0; it < degM; it += 16) {
        int e0 = p, e1 = p + 8;
        int s0 = col[e0], s1 = col[e1];
        if (e0 >= end) s0 = ZR;
        if (e1 >= end) s1 = ZR;
        uint4 v0 = *(const uint4*)(T8 + (size_t)s0 * 16 + j * 4);
        uint4 v1 = *(const uint4*)(T8 + (size_t)s1 * 16 + j * 4);
        acc16_fp8_pk(acc2, v0);
        acc16_fp8_pk(acc2, v1);
        p += 16;
    }
    float* acc = (float*)acc2;
    // reduce across the 8 slots (lane bits 2,3,4)
#pragma unroll
    for (int k = 0; k < 16; ++k) {
        acc[k] += __shfl_xor(acc[k], 4, 64);
        acc[k] += __shfl_xor(acc[k], 8, 64);
        acc[k] += __shfl_xor(acc[k], 16, 64);
    }
    float di = dinv[nd];
    const float4* b4 = (const float4*)bias;
    float r[16];
#pragma unroll
    for (int q = 0; q < 4; ++q) {
        float4 bb = b4[j * 4 + q];
        r[q * 4 + 0] = di * acc[q * 4 + 0] + bb.x;
        r[q * 4 + 1] = di * acc[q * 4 + 1] + bb.y;
        r[q * 4 + 2] = di * acc[q * 4 + 2] + bb.z;
        r[q * 4 + 3] = di * acc[q * 4 + 3] + bb.w;
    }
    // log_softmax over 64 feats: tree-max + fast exp/log + reduce over j (bits 0,1)
    float m8[8];
#pragma unroll
    for (int q = 0; q < 8; ++q) m8[q] = fmaxf(r[2 * q], r[2 * q + 1]);
#pragma unroll
    for (int q = 0; q < 4; ++q) m8[q] = fmaxf(m8[q], m8[q + 4]);
    float m = fmaxf(fmaxf(m8[0], m8[2]), fmaxf(m8[1], m8[3]));
    m = fmaxf(m, __shfl_xor(m, 1, 64));
    m = fmaxf(m, __shfl_xor(m, 2, 64));
    float e[16];
#pragma unroll
    for (int k = 0; k < 16; ++k) e[k] = __expf(r[k] - m);
#pragma unroll
    for (int q = 0; q < 8; ++q) e[q] += e[q + 8];
#pragma unroll
    for (int q = 0; q < 4; ++q) e[q] += e[q + 4];
    float ss = (e[0] + e[2]) + (e[1] + e[3]);
    ss += __shfl_xor(ss, 1, 64);
    ss += __shfl_xor(ss, 2, 64);
    float lg = m + __logf(ss);
    if (slot == 0 && valid) {
#pragma unroll
        for (int q = 0; q < 4; ++q) {
            float4 o = make_float4(r[q * 4 + 0] - lg, r[q * 4 + 1] - lg,
                                   r[q * 4 + 2] - lg, r[q * 4 + 3] - lg);
            *(float4*)(out + (size_t)node * 64 + j * 16 + q * 4) = o;
        }
    }
}

// ---------------- launcher ----------------
extern "C" void kernel_launch(void* const* d_in, const int* in_sizes, int n_in,
                              void* d_out, int out_size, void* d_ws, size_t ws_size,
                              hipStream_t stream) {
    const float* x  = (const float*)d_in[0];
    const void*  ei = d_in[1];
    const float* W1 = (const float*)d_in[2];
    const float* b1 = (const float*)d_in[3];
    const float* W2 = (const float*)d_in[4];
    const float* b2 = (const float*)d_in[5];
    const float* W3 = (const float*)d_in[6];
    const float* b3 = (const float*)d_in[7];
    float* out = (float*)d_out;

    const int n = in_sizes[0] / FIN;       // 100000
    const int E = in_sizes[1] / 2;         // 1600000

    char* p = (char*)d_ws;
    auto carve = [&](size_t bytes) {
        char* q = p;
        p += (bytes + 255) & ~(size_t)255;
        return q;
    };
    const int NB = (n + 63) / 64;
    const int NS = (n + 8191) / 8192;

    long long meanS = (long long)E * 8192 / n;
    int capS = (int)(meanS + 8 * (long long)sqrt((double)meanS) + 1024);
    capS = (capS + 15) & ~15;
    long long mean2 = (long long)E * 64 / n;
    int cap2 = (int)(mean2 + 8 * (long long)sqrt((double)mean2) + 64);
    cap2 = (cap2 + 15) & ~15;

    int*   cnt     = (int*)carve((size_t)n * 4);
    int*   rowend  = (int*)carve((size_t)n * 4);
    float* dinv    = (float*)carve((size_t)n * 4);
    // +4096 ints of padding: agg kernels read col[] unclamped past rowend
    int*   colb    = (int*)carve(((size_t)NB * cap2 + 4096) * 4);
    int*   gCnt    = (int*)carve((size_t)(16 + NB) * 4);
    int*   cnt2    = gCnt + 16;
    // T: fp8 n*128 + 256B sentinel zero-row; Hb bf16 n*128.
    size_t Tbytes = (size_t)n * 128 + 256;
    size_t Hbytes = (size_t)n * 128 * 2;
    char*  TH = carve(Tbytes + Hbytes);
    void*  T  = (void*)TH;
    unsigned short* Hb = (unsigned short*)(TH + Tbytes);
    unsigned short* Wf1 = (unsigned short*)carve(128 * 128 * 2);
    unsigned short* Wf2 = (unsigned short*)carve(128 * 128 * 2);
    unsigned short* Wf3 = (unsigned short*)carve(128 * 64 * 2);

    // split bufs alias the T+Hb region (free during preprocessing)
    size_t buf1B = ((size_t)NS * capS * 4 + 255) & ~(size_t)255;
    uint32_t* buf1 = (uint32_t*)TH;
    uint32_t* buf2 = (uint32_t*)(TH + buf1B);
    size_t avail2 = (Tbytes + Hbytes > buf1B) ? (Tbytes + Hbytes - buf1B) : 0;
    size_t maxc2 = avail2 / ((size_t)NB * 4);
    if ((size_t)cap2 > maxc2) cap2 = (int)maxc2;

    hipMemsetAsync(gCnt, 0, (size_t)(16 + NB) * 4, stream);

    const int gagg2 = ((n + 1) / 2 + 3) / 4;
    const int ggemm = (n + 63) / 64;
    const int gsplitA = (E + SP_CHUNK - 1) / SP_CHUNK;
    const int gsplitBx = (capS + SP_CHUNK - 1) / SP_CHUNK;

    splitA_kernel<<<gsplitA, 256, 0, stream>>>(ei, gCnt, buf1, E, capS);
    splitB_kernel<<<dim3(gsplitBx, NS), 256, 0, stream>>>(gCnt, buf1, cnt2, buf2, capS,
                                                          cap2, NB);
    binBC_kernel<<<NB, 256, 0, stream>>>(cnt2, buf2, cnt, dinv, rowend, colb, n, cap2);
    // zero the sentinel row (bytes [n*128, n*128+128)) AFTER splits release this region
    hipMemsetAsync(TH + (size_t)n * 128, 0, 128, stream);
    wconv_all<<<20, 256, 0, stream>>>(W1, W2, W3, Wf1, Wf2, Wf3);

    // layer 1: T(fp8) = dinv * (x @ W1) ; Hb(bf16) = relu(di*(sum T) + b1)
    gemm_mfma<128, 1, 1><<<ggemm, 256, 0, stream>>>(x, Wf1, dinv, T, n);
    agg_relu_128_fp8<<<gagg2, 256, 0, stream>>>((const uint32_t*)T, rowend, cnt, colb,
                                                dinv, b1, (uint32_t*)Hb, n);
    // layer 2
    gemm_mfma<128, 0, 1><<<ggemm, 256, 0, stream>>>(Hb, Wf2, dinv, T, n);
    agg_relu_128_fp8<<<gagg2, 256, 0, stream>>>((const uint32_t*)T, rowend, cnt, colb,
                                                dinv, b2, (uint32_t*)Hb, n);
    // layer 3: T(fp8, 64 cols) = dinv * (Hb @ W3) ; out = log_softmax(...)
    gemm_mfma<64, 0, 1><<<ggemm, 256, 0, stream>>>(Hb, Wf3, dinv, T, n);
    agg_lsm_64_fp8<<<gagg2, 256, 0, stream>>>((const uint32_t*)T, rowend, cnt, colb,
                                              dinv, b3, out, n);
}